// Round 7
// baseline (189.460 us; speedup 1.0000x reference)
//
#include <hip/hip_runtime.h>
#include <math.h>

#define B_ 256
#define I_ 512
#define H_ 512
#define BH (B_*H_)

typedef float f4v __attribute__((ext_vector_type(4)));

// ws layout (floats):
// [0, 8*BH)       : gate pre-act partials  [ks*4+g][b][k]  (split-K 2)
// [8*BH, 9*BH)    : v[b,k]

// ---------------------------------------------------------------------------
// K1: gate GEMM, standalone (uncontended). split-K x2, 32x32 tile, TK=32,
// double-buffered LDS, float4 global loads. 1024 blocks.
// ---------------------------------------------------------------------------
#define TK 32
#define LDB 34               // padded LDS row stride (floats)
#define TILE_F (TK*LDB)      // 1088 floats per operand buffer
#define NGEMM 1024

__global__ __launch_bounds__(256) void k_gates(
    const float* __restrict__ h0, const float* __restrict__ inputs,
    const float* __restrict__ Wxf, const float* __restrict__ Whf,
    const float* __restrict__ Wxi, const float* __restrict__ Whi,
    const float* __restrict__ Wxo, const float* __restrict__ Who,
    const float* __restrict__ Wxc, const float* __restrict__ w,
    float* __restrict__ pre) {

    __shared__ float smem[4 * TILE_F];   // 17408 B
    int bid = blockIdx.x;
    int tid = threadIdx.x;

    int ks = bid & 1;             // 0: inputs@Wx, 1: h0@Wh (or w)
    int m0 = ((bid >> 1) & 7) * 32;
    int n0 = (bid >> 4) * 32;     // [0,2048)
    int g  = n0 >> 9;             // 0=f,1=i,2=o,3=c
    int ko0 = n0 & 511;

    const float* Asrc = ks ? h0 : inputs;
    const float* Bsrc;
    bool wpath = false;
    if (ks == 0) {
        Bsrc = (g == 0) ? Wxf : (g == 1) ? Wxi : (g == 2) ? Wxo : Wxc;
    } else {
        if (g == 3) { Bsrc = w; wpath = true; }
        else Bsrc = (g == 0) ? Whf : (g == 1) ? Whi : Who;
    }

    int row = tid >> 3;          // 0..31
    int c4  = tid & 7;           // float4 index along k (or n for wpath)
    int tx  = tid & 15, ty = tid >> 4;

    float acc[2][2] = {{0.f, 0.f}, {0.f, 0.f}};
    float4 areg, breg;

    auto LOAD = [&](int t) {
        int kb = t * TK;
        areg = *(const float4*)&Asrc[(size_t)(m0 + row) * 512 + kb + c4 * 4];
        if (wpath)
            breg = *(const float4*)&Bsrc[(size_t)(kb + row) * 512 + ko0 + c4 * 4];
        else
            breg = *(const float4*)&Bsrc[(size_t)(ko0 + row) * 512 + kb + c4 * 4];
    };
    auto STORE = [&](int pbuf) {
        float* As = smem + pbuf * 2 * TILE_F;   // [TK][LDB]  (k-major)
        float* Bs = As + TILE_F;
        #pragma unroll
        for (int j = 0; j < 4; ++j)
            As[(c4 * 4 + j) * LDB + row] = ((const float*)&areg)[j];
        if (wpath) {
            #pragma unroll
            for (int j = 0; j < 4; ++j)
                Bs[row * LDB + c4 * 4 + j] = ((const float*)&breg)[j];
        } else {
            #pragma unroll
            for (int j = 0; j < 4; ++j)
                Bs[(c4 * 4 + j) * LDB + row] = ((const float*)&breg)[j];
        }
    };

    LOAD(0);
    STORE(0);
    for (int t = 0; t < 16; ++t) {
        __syncthreads();
        if (t < 15) LOAD(t + 1);
        int pb = t & 1;
        const float* As = smem + pb * 2 * TILE_F;
        const float* Bs = As + TILE_F;
        #pragma unroll
        for (int kk = 0; kk < TK; ++kk) {
            float2 a2 = *(const float2*)&As[kk * LDB + ty * 2];
            float2 b2 = *(const float2*)&Bs[kk * LDB + tx * 2];
            acc[0][0] += a2.x * b2.x; acc[0][1] += a2.x * b2.y;
            acc[1][0] += a2.y * b2.x; acc[1][1] += a2.y * b2.y;
        }
        if (t < 15) STORE(pb ^ 1);
    }

    float* pb_out = pre + (size_t)(ks * 4 + g) * BH;
    #pragma unroll
    for (int i = 0; i < 2; ++i) {
        #pragma unroll
        for (int j = 0; j < 2; ++j) {
            int bnum = m0 + ty * 2 + i;
            int ko = ko0 + tx * 2 + j;
            pb_out[(size_t)bnum * H_ + ko] = acc[i][j];
        }
    }
}

// ---------------------------------------------------------------------------
// K2: per-sample hebbdot + finalize fused. One block (512 thr) per sample:
// stream hebb[b] (1 MB, L3-resident in steady state), reduce dot[k] in LDS,
// then inline gate activations, outputs, myeta, v.
// ---------------------------------------------------------------------------
__global__ __launch_bounds__(512) void k_dotfin(
    const float* __restrict__ hebb, const float* __restrict__ h0,
    const float* __restrict__ pre, const float* __restrict__ c0,
    const float* __restrict__ alpha,
    const float* __restrict__ bxf, const float* __restrict__ bhf,
    const float* __restrict__ bxi, const float* __restrict__ bhi,
    const float* __restrict__ bxo, const float* __restrict__ bho,
    const float* __restrict__ bxc,
    const float* __restrict__ Wmod, const float* __restrict__ bmod,
    const float* __restrict__ Wfan, const float* __restrict__ bfan,
    float* __restrict__ out, float* __restrict__ v) {

    __shared__ float h0s[H_];            // 2 KB
    __shared__ float plds[4 * H_];       // 8 KB  (partials per h-group)
    __shared__ float red[8];

    int b = blockIdx.x;
    int t = threadIdx.x;

    h0s[t & 511] = h0[(size_t)b * H_ + (t & 511)];
    __syncthreads();

    // ---- phase A: dot[k] = sum_h h0[b,h]*hebb[b,h,k] ----
    int hg = t >> 7;          // 0..3 (h-group of 128 rows)
    int k4 = t & 127;         // float4 column
    const float4* hb4 = (const float4*)hebb + ((size_t)b << 16);
    float4 acc = make_float4(0.f, 0.f, 0.f, 0.f);
    #pragma unroll 8
    for (int r = 0; r < 128; ++r) {
        int h = (hg << 7) + r;
        float s = h0s[h];
        float4 vv = hb4[(size_t)h * 128 + k4];
        acc.x += s * vv.x; acc.y += s * vv.y;
        acc.z += s * vv.z; acc.w += s * vv.w;
    }
    ((float4*)plds)[hg * 128 + k4] = acc;
    __syncthreads();

    // ---- phase B: finalize, one k per thread ----
    int k = t;                // 0..511
    float dot = plds[k] + plds[H_ + k] + plds[2 * H_ + k] + plds[3 * H_ + k];
    size_t off = (size_t)b * H_ + k;
    float pf = pre[0 * BH + off] + pre[4 * BH + off] + bxf[k] + bhf[k];
    float pi = pre[1 * BH + off] + pre[5 * BH + off] + bxi[k] + bhi[k];
    float po = pre[2 * BH + off] + pre[6 * BH + off] + bxo[k] + bho[k];
    float pc = pre[3 * BH + off] + pre[7 * BH + off] + bxc[k];
    float c2 = tanhf(pc + alpha[k] * dot);
    float fg = 1.f / (1.f + expf(-pf));
    float ig = 1.f / (1.f + expf(-pi));
    float og = 1.f / (1.f + expf(-po));
    float cell = fg * c0[off] + ig * c2;
    float ha = og * tanhf(cell);
    out[off] = ha;                 // hactiv
    out[BH + off] = cell;          // cell

    // myeta = tanh(sum_k ha*Wmod[k] + bmod)
    float x = ha * Wmod[k];
    #pragma unroll
    for (int o = 32; o > 0; o >>= 1) x += __shfl_down(x, o, 64);
    int wid = t >> 6, lane = t & 63;
    if (lane == 0) red[wid] = x;
    __syncthreads();
    float s8 = red[0] + red[1] + red[2] + red[3]
             + red[4] + red[5] + red[6] + red[7];
    float myeta = tanhf(s8 + bmod[0]);
    v[off] = (myeta * Wfan[k] + bfan[k]) * c2;
}

// ---------------------------------------------------------------------------
// K3: hebb_new = clip(hebb + h0[b,h]*v[b,k], -2, 2)
// Reverse-order stream (freshest L3 lines first) + NT stores.
// ---------------------------------------------------------------------------
__global__ __launch_bounds__(256) void k_update(
    const float4* __restrict__ hebb, const float* __restrict__ h0,
    const float* __restrict__ v, float* __restrict__ out) {
    const int total = B_ * H_ * (H_ / 4);   // 16,777,216 float4
    int stride = gridDim.x * blockDim.x;    // 524,288
    int base = blockIdx.x * blockDim.x + threadIdx.x;
    for (int f = total - stride + base; f >= 0; f -= stride) {
        int k4 = f & 127;           // float4 col
        int h  = (f >> 7) & 511;
        int b  = f >> 16;
        float u = h0[(b << 9) + h];
        const float4* vv4 = (const float4*)v;
        float4 vv = vv4[(b << 7) + k4];
        float4 hb = hebb[f];
        f4v r;
        r.x = fminf(fmaxf(hb.x + u * vv.x, -2.f), 2.f);
        r.y = fminf(fmaxf(hb.y + u * vv.y, -2.f), 2.f);
        r.z = fminf(fmaxf(hb.z + u * vv.z, -2.f), 2.f);
        r.w = fminf(fmaxf(hb.w + u * vv.w, -2.f), 2.f);
        __builtin_nontemporal_store(r, (f4v*)(out) + f);
    }
}

// ---------------------------------------------------------------------------
extern "C" void kernel_launch(void* const* d_in, const int* in_sizes, int n_in,
                              void* d_out, int out_size, void* d_ws, size_t ws_size,
                              hipStream_t stream) {
    const float* inputs = (const float*)d_in[0];
    const float* h0     = (const float*)d_in[1];
    const float* c0     = (const float*)d_in[2];
    const float* hebb   = (const float*)d_in[3];
    const float* w      = (const float*)d_in[4];
    const float* alpha  = (const float*)d_in[5];
    const float* Wxf = (const float*)d_in[6];  const float* bxf = (const float*)d_in[7];
    const float* Whf = (const float*)d_in[8];  const float* bhf = (const float*)d_in[9];
    const float* Wxi = (const float*)d_in[10]; const float* bxi = (const float*)d_in[11];
    const float* Whi = (const float*)d_in[12]; const float* bhi = (const float*)d_in[13];
    const float* Wxo = (const float*)d_in[14]; const float* bxo = (const float*)d_in[15];
    const float* Who = (const float*)d_in[16]; const float* bho = (const float*)d_in[17];
    const float* Wxc = (const float*)d_in[18]; const float* bxc = (const float*)d_in[19];
    const float* Wmod = (const float*)d_in[20]; const float* bmod = (const float*)d_in[21];
    const float* Wfan = (const float*)d_in[22]; const float* bfan = (const float*)d_in[23];

    float* out = (float*)d_out;
    float* ws  = (float*)d_ws;
    float* pre  = ws;                  // 8*BH (split-K partials)
    float* vbuf = ws + 8 * BH;         // BH

    // 1) gate GEMM, uncontended
    k_gates<<<NGEMM, 256, 0, stream>>>(h0, inputs,
        Wxf, Whf, Wxi, Whi, Wxo, Who, Wxc, w, pre);
    // 2) per-sample hebbdot + finalize
    k_dotfin<<<B_, 512, 0, stream>>>(hebb, h0, pre, c0, alpha,
        bxf, bhf, bxi, bhi, bxo, bho, bxc,
        Wmod, bmod, Wfan, bfan, out, vbuf);
    // 3) hebb update (reverse stream + NT stores)
    k_update<<<2048, 256, 0, stream>>>((const float4*)hebb, h0, vbuf,
                                       out + 2 * BH);
}

// Round 8
// 188.964 us; speedup vs baseline: 1.0026x; 1.0026x over previous
//
#include <hip/hip_runtime.h>
#include <hip/hip_bf16.h>
#include <math.h>

#define B_ 256
#define I_ 512
#define H_ 512
#define BH (B_*H_)
#define KA 1024          // concat K ([inputs | h0])

typedef float f4v  __attribute__((ext_vector_type(4)));
typedef short s8v  __attribute__((ext_vector_type(8)));   // 8 bf16 (4 VGPRs)
typedef float f32x4 __attribute__((ext_vector_type(4)));

// ws layout (floats):
// [0, 4*BH)        : pre[g][b][k]  gate pre-acts WITH biases  (2 MB)
// [4*BH, 5*BH)     : v[b,k]
// [5*BH, ...)      : bf16 planes: Ahi(128K fl) Alo(128K) Bhi(1M) Blo(1M)

#define A_ELEMS (256*1024)
#define B_ELEMS (2048*1024)

// ---------------------------------------------------------------------------
// K0: fp32 -> split-bf16 (hi/lo) planes. A = [inputs | h0] (256 x 1024),
// B^T = [2048 n][1024 k]: n=g*512+ko; k<512 -> Wxg[ko][k]; k>=512 ->
// g<3 ? Whg[ko][k-512] : w[k-512][ko]  (w transposed here, once).
// ---------------------------------------------------------------------------
__global__ __launch_bounds__(256) void k_convert(
    const float* __restrict__ inputs, const float* __restrict__ h0,
    const float* __restrict__ Wxf, const float* __restrict__ Whf,
    const float* __restrict__ Wxi, const float* __restrict__ Whi,
    const float* __restrict__ Wxo, const float* __restrict__ Who,
    const float* __restrict__ Wxc, const float* __restrict__ w,
    ushort* __restrict__ Ahi, ushort* __restrict__ Alo,
    ushort* __restrict__ Bhi, ushort* __restrict__ Blo) {
    const int NTOT = A_ELEMS + B_ELEMS;
    int stride = gridDim.x * blockDim.x;
    for (int f = blockIdx.x * blockDim.x + threadIdx.x; f < NTOT; f += stride) {
        float x; ushort* dhi; ushort* dlo; int idx;
        if (f < A_ELEMS) {
            idx = f;
            int m = f >> 10, k = f & 1023;
            x = (k < 512) ? inputs[m * 512 + k] : h0[m * 512 + (k - 512)];
            dhi = Ahi; dlo = Alo;
        } else {
            idx = f - A_ELEMS;
            int n = idx >> 10, k = idx & 1023;
            int g = n >> 9, ko = n & 511;
            if (k < 512) {
                const float* W = (g == 0) ? Wxf : (g == 1) ? Wxi : (g == 2) ? Wxo : Wxc;
                x = W[ko * 512 + k];
            } else if (g < 3) {
                const float* W = (g == 0) ? Whf : (g == 1) ? Whi : Who;
                x = W[ko * 512 + (k - 512)];
            } else {
                x = w[(size_t)(k - 512) * 512 + ko];   // transpose of w
            }
            dhi = Bhi; dlo = Blo;
        }
        __hip_bfloat16 h = __float2bfloat16(x);
        float hf = __bfloat162float(h);
        __hip_bfloat16 l = __float2bfloat16(x - hf);
        dhi[idx] = *(ushort*)&h;
        dlo[idx] = *(ushort*)&l;
    }
}

// ---------------------------------------------------------------------------
// K1: gate GEMM via split-bf16 MFMA. One wave per 16x16 output tile;
// K=1024 in 32 chunks; per chunk 3 MFMAs (hi*hi + hi*lo + lo*hi).
// No LDS, no barriers. 2048 tiles = 512 blocks x 4 waves.
// ---------------------------------------------------------------------------
__global__ __launch_bounds__(256) void k_mfma_gates(
    const ushort* __restrict__ Ahi, const ushort* __restrict__ Alo,
    const ushort* __restrict__ Bhi, const ushort* __restrict__ Blo,
    const float* __restrict__ bxf, const float* __restrict__ bhf,
    const float* __restrict__ bxi, const float* __restrict__ bhi,
    const float* __restrict__ bxo, const float* __restrict__ bho,
    const float* __restrict__ bxc,
    float* __restrict__ pre) {
    int wave = threadIdx.x >> 6, lane = threadIdx.x & 63;
    int tile = blockIdx.x * 4 + wave;        // 0..2047
    int m0 = (tile & 15) << 4;               // batch tile
    int n0 = (tile >> 4) << 4;               // virtual gate column tile
    int r  = lane & 15;                      // row within A / B^T tile
    int kg = lane >> 4;                      // k-group (0..3), 8 bf16 each

    const s8v* pa_hi = (const s8v*)(Ahi + (size_t)(m0 + r) * KA + kg * 8);
    const s8v* pa_lo = (const s8v*)(Alo + (size_t)(m0 + r) * KA + kg * 8);
    const s8v* pb_hi = (const s8v*)(Bhi + (size_t)(n0 + r) * KA + kg * 8);
    const s8v* pb_lo = (const s8v*)(Blo + (size_t)(n0 + r) * KA + kg * 8);

    f32x4 acc = {0.f, 0.f, 0.f, 0.f};
    #pragma unroll 4
    for (int kc = 0; kc < 32; ++kc) {
        s8v ah = pa_hi[kc * 4];
        s8v al = pa_lo[kc * 4];
        s8v bh = pb_hi[kc * 4];
        s8v bl = pb_lo[kc * 4];
        acc = __builtin_amdgcn_mfma_f32_16x16x32_bf16(ah, bh, acc, 0, 0, 0);
        acc = __builtin_amdgcn_mfma_f32_16x16x32_bf16(ah, bl, acc, 0, 0, 0);
        acc = __builtin_amdgcn_mfma_f32_16x16x32_bf16(al, bh, acc, 0, 0, 0);
    }

    int g  = n0 >> 9;
    int ko = (n0 & 511) + r;                 // C/D: col = lane&15
    float bias;
    if (g == 0)      bias = bxf[ko] + bhf[ko];
    else if (g == 1) bias = bxi[ko] + bhi[ko];
    else if (g == 2) bias = bxo[ko] + bho[ko];
    else             bias = bxc[ko];
    #pragma unroll
    for (int j = 0; j < 4; ++j) {            // C/D: row = kg*4 + j
        int m = m0 + kg * 4 + j;
        pre[(size_t)g * BH + (size_t)m * H_ + ko] = acc[j] + bias;
    }
}

// ---------------------------------------------------------------------------
// K2: per-sample hebbdot + finalize. One 512-thr block per sample: stream
// hebb[b] (1 MB), reduce dot[k] in LDS, then activations, outputs, myeta, v.
// ---------------------------------------------------------------------------
__global__ __launch_bounds__(512) void k_dotfin(
    const float* __restrict__ hebb, const float* __restrict__ h0,
    const float* __restrict__ pre, const float* __restrict__ c0,
    const float* __restrict__ alpha,
    const float* __restrict__ Wmod, const float* __restrict__ bmod,
    const float* __restrict__ Wfan, const float* __restrict__ bfan,
    float* __restrict__ out, float* __restrict__ v) {

    __shared__ float h0s[H_];            // 2 KB
    __shared__ float plds[4 * H_];       // 8 KB
    __shared__ float red[8];

    int b = blockIdx.x;
    int t = threadIdx.x;

    h0s[t & 511] = h0[(size_t)b * H_ + (t & 511)];
    __syncthreads();

    // ---- phase A: dot[k] = sum_h h0[b,h]*hebb[b,h,k] ----
    int hg = t >> 7;          // 0..3
    int k4 = t & 127;
    const float4* hb4 = (const float4*)hebb + ((size_t)b << 16);
    float4 acc = make_float4(0.f, 0.f, 0.f, 0.f);
    #pragma unroll 8
    for (int r = 0; r < 128; ++r) {
        int h = (hg << 7) + r;
        float s = h0s[h];
        float4 vv = hb4[(size_t)h * 128 + k4];
        acc.x += s * vv.x; acc.y += s * vv.y;
        acc.z += s * vv.z; acc.w += s * vv.w;
    }
    ((float4*)plds)[hg * 128 + k4] = acc;
    __syncthreads();

    // ---- phase B: finalize, one k per thread ----
    int k = t;
    float dot = plds[k] + plds[H_ + k] + plds[2 * H_ + k] + plds[3 * H_ + k];
    size_t off = (size_t)b * H_ + k;
    float pf = pre[0 * BH + off];
    float pi = pre[1 * BH + off];
    float po = pre[2 * BH + off];
    float pc = pre[3 * BH + off];
    float c2 = tanhf(pc + alpha[k] * dot);
    float fg = 1.f / (1.f + expf(-pf));
    float ig = 1.f / (1.f + expf(-pi));
    float og = 1.f / (1.f + expf(-po));
    float cell = fg * c0[off] + ig * c2;
    float ha = og * tanhf(cell);
    out[off] = ha;                 // hactiv
    out[BH + off] = cell;          // cell

    float x = ha * Wmod[k];
    #pragma unroll
    for (int o = 32; o > 0; o >>= 1) x += __shfl_down(x, o, 64);
    int wid = t >> 6, lane = t & 63;
    if (lane == 0) red[wid] = x;
    __syncthreads();
    float s8 = red[0] + red[1] + red[2] + red[3]
             + red[4] + red[5] + red[6] + red[7];
    float myeta = tanhf(s8 + bmod[0]);
    v[off] = (myeta * Wfan[k] + bfan[k]) * c2;
}

// ---------------------------------------------------------------------------
// K3: hebb_new = clip(hebb + h0[b,h]*v[b,k], -2, 2)
// Reverse-order stream (freshest L3 lines first) + NT stores.
// ---------------------------------------------------------------------------
__global__ __launch_bounds__(256) void k_update(
    const float4* __restrict__ hebb, const float* __restrict__ h0,
    const float* __restrict__ v, float* __restrict__ out) {
    const int total = B_ * H_ * (H_ / 4);   // 16,777,216 float4
    int stride = gridDim.x * blockDim.x;    // 524,288
    int base = blockIdx.x * blockDim.x + threadIdx.x;
    for (int f = total - stride + base; f >= 0; f -= stride) {
        int k4 = f & 127;
        int h  = (f >> 7) & 511;
        int b  = f >> 16;
        float u = h0[(b << 9) + h];
        const float4* vv4 = (const float4*)v;
        float4 vv = vv4[(b << 7) + k4];
        float4 hb = hebb[f];
        f4v r;
        r.x = fminf(fmaxf(hb.x + u * vv.x, -2.f), 2.f);
        r.y = fminf(fmaxf(hb.y + u * vv.y, -2.f), 2.f);
        r.z = fminf(fmaxf(hb.z + u * vv.z, -2.f), 2.f);
        r.w = fminf(fmaxf(hb.w + u * vv.w, -2.f), 2.f);
        __builtin_nontemporal_store(r, (f4v*)(out) + f);
    }
}

// ---------------------------------------------------------------------------
extern "C" void kernel_launch(void* const* d_in, const int* in_sizes, int n_in,
                              void* d_out, int out_size, void* d_ws, size_t ws_size,
                              hipStream_t stream) {
    const float* inputs = (const float*)d_in[0];
    const float* h0     = (const float*)d_in[1];
    const float* c0     = (const float*)d_in[2];
    const float* hebb   = (const float*)d_in[3];
    const float* w      = (const float*)d_in[4];
    const float* alpha  = (const float*)d_in[5];
    const float* Wxf = (const float*)d_in[6];  const float* bxf = (const float*)d_in[7];
    const float* Whf = (const float*)d_in[8];  const float* bhf = (const float*)d_in[9];
    const float* Wxi = (const float*)d_in[10]; const float* bxi = (const float*)d_in[11];
    const float* Whi = (const float*)d_in[12]; const float* bhi = (const float*)d_in[13];
    const float* Wxo = (const float*)d_in[14]; const float* bxo = (const float*)d_in[15];
    const float* Who = (const float*)d_in[16]; const float* bho = (const float*)d_in[17];
    const float* Wxc = (const float*)d_in[18]; const float* bxc = (const float*)d_in[19];
    const float* Wmod = (const float*)d_in[20]; const float* bmod = (const float*)d_in[21];
    const float* Wfan = (const float*)d_in[22]; const float* bfan = (const float*)d_in[23];

    float* out = (float*)d_out;
    float* ws  = (float*)d_ws;
    float*  pre  = ws;                        // 4*BH floats
    float*  vbuf = ws + 4 * BH;               // BH floats
    ushort* Ahi  = (ushort*)(ws + 5 * BH);
    ushort* Alo  = Ahi + A_ELEMS;
    ushort* Bhi  = Alo + A_ELEMS;
    ushort* Blo  = Bhi + B_ELEMS;

    // 0) split-bf16 conversion (~19 MB traffic)
    k_convert<<<2048, 256, 0, stream>>>(inputs, h0,
        Wxf, Whf, Wxi, Whi, Wxo, Who, Wxc, w, Ahi, Alo, Bhi, Blo);
    // 1) gate GEMM on matrix cores (biases folded in)
    k_mfma_gates<<<512, 256, 0, stream>>>(Ahi, Alo, Bhi, Blo,
        bxf, bhf, bxi, bhi, bxo, bho, bxc, pre);
    // 2) per-sample hebbdot + finalize
    k_dotfin<<<B_, 512, 0, stream>>>(hebb, h0, pre, c0, alpha,
        Wmod, bmod, Wfan, bfan, out, vbuf);
    // 3) hebb update (reverse stream + NT stores)
    k_update<<<2048, 256, 0, stream>>>((const float4*)hebb, h0, vbuf,
                                       out + 2 * BH);
}

// Round 9
// 188.173 us; speedup vs baseline: 1.0068x; 1.0042x over previous
//
#include <hip/hip_runtime.h>
#include <hip/hip_bf16.h>
#include <math.h>

#define B_ 256
#define I_ 512
#define H_ 512
#define BH (B_*H_)
#define KA 1024          // concat K ([inputs | h0])
#define NCH 8            // h-chunks for hebbdot partials
#define HCH (H_/NCH)     // 64

typedef float f4v  __attribute__((ext_vector_type(4)));
typedef short s8v  __attribute__((ext_vector_type(8)));   // 8 bf16 (4 VGPRs)
typedef float f32x4 __attribute__((ext_vector_type(4)));

// ws layout (floats):
// [0, 4*BH)        : pre[g][b][k]  gate pre-acts WITH biases
// [4*BH, 12*BH)    : part[ch][b][k] hebbdot partials
// [12*BH, 13*BH)   : v[b,k]
// [13*BH, ...)     : bf16 planes Ahi, Alo, Bhi, Blo

#define A_ELEMS (256*1024)
#define B_ELEMS (2048*1024)

// ---------------------------------------------------------------------------
// K0: fp32 -> split-bf16 (hi/lo) planes. A = [inputs | h0] (256 x 1024),
// B^T = [2048 n][1024 k]: k<512 -> Wxg[ko][k]; k>=512 ->
// g<3 ? Whg[ko][k-512] : w[k-512][ko]  (w transposed here, once).
// ---------------------------------------------------------------------------
__global__ __launch_bounds__(256) void k_convert(
    const float* __restrict__ inputs, const float* __restrict__ h0,
    const float* __restrict__ Wxf, const float* __restrict__ Whf,
    const float* __restrict__ Wxi, const float* __restrict__ Whi,
    const float* __restrict__ Wxo, const float* __restrict__ Who,
    const float* __restrict__ Wxc, const float* __restrict__ w,
    ushort* __restrict__ Ahi, ushort* __restrict__ Alo,
    ushort* __restrict__ Bhi, ushort* __restrict__ Blo) {
    const int NTOT = A_ELEMS + B_ELEMS;
    int stride = gridDim.x * blockDim.x;
    for (int f = blockIdx.x * blockDim.x + threadIdx.x; f < NTOT; f += stride) {
        float x; ushort* dhi; ushort* dlo; int idx;
        if (f < A_ELEMS) {
            idx = f;
            int m = f >> 10, k = f & 1023;
            x = (k < 512) ? inputs[m * 512 + k] : h0[m * 512 + (k - 512)];
            dhi = Ahi; dlo = Alo;
        } else {
            idx = f - A_ELEMS;
            int n = idx >> 10, k = idx & 1023;
            int g = n >> 9, ko = n & 511;
            if (k < 512) {
                const float* W = (g == 0) ? Wxf : (g == 1) ? Wxi : (g == 2) ? Wxo : Wxc;
                x = W[ko * 512 + k];
            } else if (g < 3) {
                const float* W = (g == 0) ? Whf : (g == 1) ? Whi : Who;
                x = W[ko * 512 + (k - 512)];
            } else {
                x = w[(size_t)(k - 512) * 512 + ko];   // transpose of w
            }
            dhi = Bhi; dlo = Blo;
        }
        __hip_bfloat16 h = __float2bfloat16(x);
        float hf = __bfloat162float(h);
        __hip_bfloat16 l = __float2bfloat16(x - hf);
        dhi[idx] = *(ushort*)&h;
        dlo[idx] = *(ushort*)&l;
    }
}

// ---------------------------------------------------------------------------
// K1: gate GEMM via split-bf16 MFMA. One wave per 16x16 output tile;
// K=1024 in 32 chunks; 3 MFMAs per chunk (hi*hi + hi*lo + lo*hi).
// No LDS, no barriers. Biases folded in.
// ---------------------------------------------------------------------------
__global__ __launch_bounds__(256) void k_mfma_gates(
    const ushort* __restrict__ Ahi, const ushort* __restrict__ Alo,
    const ushort* __restrict__ Bhi, const ushort* __restrict__ Blo,
    const float* __restrict__ bxf, const float* __restrict__ bhf,
    const float* __restrict__ bxi, const float* __restrict__ bhi,
    const float* __restrict__ bxo, const float* __restrict__ bho,
    const float* __restrict__ bxc,
    float* __restrict__ pre) {
    int wave = threadIdx.x >> 6, lane = threadIdx.x & 63;
    int tile = blockIdx.x * 4 + wave;        // 0..2047
    int m0 = (tile & 15) << 4;               // batch tile
    int n0 = (tile >> 4) << 4;               // virtual gate column tile
    int r  = lane & 15;
    int kg = lane >> 4;                      // k-group (0..3), 8 bf16 each

    const s8v* pa_hi = (const s8v*)(Ahi + (size_t)(m0 + r) * KA + kg * 8);
    const s8v* pa_lo = (const s8v*)(Alo + (size_t)(m0 + r) * KA + kg * 8);
    const s8v* pb_hi = (const s8v*)(Bhi + (size_t)(n0 + r) * KA + kg * 8);
    const s8v* pb_lo = (const s8v*)(Blo + (size_t)(n0 + r) * KA + kg * 8);

    f32x4 acc = {0.f, 0.f, 0.f, 0.f};
    #pragma unroll 4
    for (int kc = 0; kc < 32; ++kc) {
        s8v ah = pa_hi[kc * 4];
        s8v al = pa_lo[kc * 4];
        s8v bh = pb_hi[kc * 4];
        s8v bl = pb_lo[kc * 4];
        acc = __builtin_amdgcn_mfma_f32_16x16x32_bf16(ah, bh, acc, 0, 0, 0);
        acc = __builtin_amdgcn_mfma_f32_16x16x32_bf16(ah, bl, acc, 0, 0, 0);
        acc = __builtin_amdgcn_mfma_f32_16x16x32_bf16(al, bh, acc, 0, 0, 0);
    }

    int g  = n0 >> 9;
    int ko = (n0 & 511) + r;                 // C/D: col = lane&15
    float bias;
    if (g == 0)      bias = bxf[ko] + bhf[ko];
    else if (g == 1) bias = bxi[ko] + bhi[ko];
    else if (g == 2) bias = bxo[ko] + bho[ko];
    else             bias = bxc[ko];
    #pragma unroll
    for (int j = 0; j < 4; ++j) {            // C/D: row = kg*4 + j
        int m = m0 + kg * 4 + j;
        pre[(size_t)g * BH + (size_t)m * H_ + ko] = acc[j] + bias;
    }
}

// ---------------------------------------------------------------------------
// K2: hebbdot partials, 2048 blocks (8/CU -> 32 waves/CU, full MLP).
// part[ch][b][k] = sum_{h in 64-chunk} h0[b,h]*hebb[b,h,k]
// ---------------------------------------------------------------------------
__global__ __launch_bounds__(256) void k_hebbdot(
    const float* __restrict__ hebb, const float* __restrict__ h0,
    float* __restrict__ part) {
    __shared__ float h0s[HCH];
    __shared__ float4 red[256];
    int hbid = blockIdx.x;
    int b  = hbid >> 3;    // consecutive blocks share b -> contiguous hebb
    int ch = hbid & 7;
    int tid = threadIdx.x;

    if (tid < HCH) h0s[tid] = h0[b * H_ + ch * HCH + tid];
    __syncthreads();

    const float4* hbp = (const float4*)(hebb + ((size_t)b * H_ + (size_t)ch * HCH) * H_);
    int tk = tid & 127;    // float4 column
    int th = tid >> 7;     // 0,1 — split h range
    float4 acc = make_float4(0.f, 0.f, 0.f, 0.f);
    #pragma unroll 8
    for (int r = 0; r < 32; ++r) {
        int hh = th * 32 + r;
        float s = h0s[hh];
        float4 vv = hbp[(size_t)hh * 128 + tk];
        acc.x += s * vv.x; acc.y += s * vv.y;
        acc.z += s * vv.z; acc.w += s * vv.w;
    }
    red[tid] = acc;
    __syncthreads();
    if (tid < 128) {
        float4 a = red[tid], c = red[tid + 128];
        float4 o = make_float4(a.x + c.x, a.y + c.y, a.z + c.z, a.w + c.w);
        ((float4*)(part + ((size_t)ch * B_ + b) * H_))[tid] = o;
    }
}

// ---------------------------------------------------------------------------
// K3: finalize per sample (pre already has biases)
// ---------------------------------------------------------------------------
__global__ __launch_bounds__(256) void k_finalize(
    const float* __restrict__ pre, const float* __restrict__ part,
    const float* __restrict__ c0, const float* __restrict__ alpha,
    const float* __restrict__ Wmod, const float* __restrict__ bmod,
    const float* __restrict__ Wfan, const float* __restrict__ bfan,
    float* __restrict__ out, float* __restrict__ v) {

    int b = blockIdx.x;
    int t = threadIdx.x;

    float c2r[2];
    float local = 0.f;
    #pragma unroll
    for (int s = 0; s < 2; ++s) {
        int k = t + s * 256;
        float dot = 0.f;
        #pragma unroll
        for (int c = 0; c < NCH; ++c) dot += part[((size_t)c * B_ + b) * H_ + k];
        size_t off = (size_t)b * H_ + k;
        float pf = pre[0 * BH + off];
        float pi = pre[1 * BH + off];
        float po = pre[2 * BH + off];
        float pc = pre[3 * BH + off];
        float c2 = tanhf(pc + alpha[k] * dot);
        float fg = 1.f / (1.f + expf(-pf));
        float ig = 1.f / (1.f + expf(-pi));
        float og = 1.f / (1.f + expf(-po));
        float cell = fg * c0[off] + ig * c2;
        float ha = og * tanhf(cell);
        out[off] = ha;                 // hactiv
        out[BH + off] = cell;          // cell
        c2r[s] = c2;
        local += ha * Wmod[k];
    }
    float x = local;
    #pragma unroll
    for (int o = 32; o > 0; o >>= 1) x += __shfl_down(x, o, 64);
    __shared__ float red[4];
    int wid = t >> 6, lane = t & 63;
    if (lane == 0) red[wid] = x;
    __syncthreads();
    float s4 = red[0] + red[1] + red[2] + red[3];
    float myeta = tanhf(s4 + bmod[0]);
    #pragma unroll
    for (int s = 0; s < 2; ++s) {
        int k = t + s * 256;
        size_t off = (size_t)b * H_ + k;
        v[off] = (myeta * Wfan[k] + bfan[k]) * c2r[s];
    }
}

// ---------------------------------------------------------------------------
// K4: hebb_new = clip(hebb + h0[b,h]*v[b,k], -2, 2)
// Reverse-order stream (freshest L3 lines first) + NT stores.
// ---------------------------------------------------------------------------
__global__ __launch_bounds__(256) void k_update(
    const float4* __restrict__ hebb, const float* __restrict__ h0,
    const float* __restrict__ v, float* __restrict__ out) {
    const int total = B_ * H_ * (H_ / 4);   // 16,777,216 float4
    int stride = gridDim.x * blockDim.x;    // 524,288
    int base = blockIdx.x * blockDim.x + threadIdx.x;
    for (int f = total - stride + base; f >= 0; f -= stride) {
        int k4 = f & 127;
        int h  = (f >> 7) & 511;
        int b  = f >> 16;
        float u = h0[(b << 9) + h];
        const float4* vv4 = (const float4*)v;
        float4 vv = vv4[(b << 7) + k4];
        float4 hb = hebb[f];
        f4v r;
        r.x = fminf(fmaxf(hb.x + u * vv.x, -2.f), 2.f);
        r.y = fminf(fmaxf(hb.y + u * vv.y, -2.f), 2.f);
        r.z = fminf(fmaxf(hb.z + u * vv.z, -2.f), 2.f);
        r.w = fminf(fmaxf(hb.w + u * vv.w, -2.f), 2.f);
        __builtin_nontemporal_store(r, (f4v*)(out) + f);
    }
}

// ---------------------------------------------------------------------------
extern "C" void kernel_launch(void* const* d_in, const int* in_sizes, int n_in,
                              void* d_out, int out_size, void* d_ws, size_t ws_size,
                              hipStream_t stream) {
    const float* inputs = (const float*)d_in[0];
    const float* h0     = (const float*)d_in[1];
    const float* c0     = (const float*)d_in[2];
    const float* hebb   = (const float*)d_in[3];
    const float* w      = (const float*)d_in[4];
    const float* alpha  = (const float*)d_in[5];
    const float* Wxf = (const float*)d_in[6];  const float* bxf = (const float*)d_in[7];
    const float* Whf = (const float*)d_in[8];  const float* bhf = (const float*)d_in[9];
    const float* Wxi = (const float*)d_in[10]; const float* bxi = (const float*)d_in[11];
    const float* Whi = (const float*)d_in[12]; const float* bhi = (const float*)d_in[13];
    const float* Wxo = (const float*)d_in[14]; const float* bxo = (const float*)d_in[15];
    const float* Who = (const float*)d_in[16]; const float* bho = (const float*)d_in[17];
    const float* Wxc = (const float*)d_in[18]; const float* bxc = (const float*)d_in[19];
    const float* Wmod = (const float*)d_in[20]; const float* bmod = (const float*)d_in[21];
    const float* Wfan = (const float*)d_in[22]; const float* bfan = (const float*)d_in[23];

    float* out = (float*)d_out;
    float* ws  = (float*)d_ws;
    float*  pre  = ws;                        // 4*BH
    float*  part = ws + 4 * BH;               // 8*BH
    float*  vbuf = ws + 12 * BH;              // BH
    ushort* Ahi  = (ushort*)(ws + 13 * BH);
    ushort* Alo  = Ahi + A_ELEMS;
    ushort* Bhi  = Alo + A_ELEMS;
    ushort* Blo  = Bhi + B_ELEMS;

    // 0) split-bf16 conversion
    k_convert<<<2048, 256, 0, stream>>>(inputs, h0,
        Wxf, Whf, Wxi, Whi, Wxo, Who, Wxc, w, Ahi, Alo, Bhi, Blo);
    // 1) gate GEMM on matrix cores (biases folded)
    k_mfma_gates<<<512, 256, 0, stream>>>(Ahi, Alo, Bhi, Blo,
        bxf, bhf, bxi, bhi, bxo, bho, bxc, pre);
    // 2) hebbdot partials at full occupancy (8 blocks/CU)
    k_hebbdot<<<B_ * NCH, 256, 0, stream>>>(hebb, h0, part);
    // 3) finalize
    k_finalize<<<B_, 256, 0, stream>>>(pre, part, c0, alpha,
                                       Wmod, bmod, Wfan, bfan, out, vbuf);
    // 4) hebb update (reverse stream + NT stores)
    k_update<<<2048, 256, 0, stream>>>((const float4*)hebb, h0, vbuf,
                                       out + 2 * BH);
}